// Round 11
// baseline (50.308 us; speedup 1.0000x reference)
//
#include <hip/hip_runtime.h>
#include <hip/hip_bf16.h>
#include <stdint.h>

// PairRelationEncoder: out[b,e,s] = b2[s] + sum_r W2[s,r]*relu(b1[r] + sum_f W1[r,f]*pair[b,e,f])
// pair = [zi, zj, zi-zj, zi*zj] folded to [zi, zj, zi*zj]: Wzi=W1a+W1c, Wzj=W1b-W1c, Wpr=W1d.
// B=4 N=4096 D=64 E=131072 R=64. Out f32 (4,131072,64).
//
// R11: CUT LDS TRAFFIC 2.4x. R10's body issues 88 LDS b128 reads per 32 pairs (68 weight +
// 16 bias-init + 4 h1) ~= 24us of LDS pipe per CU -- the largest component after the HBM
// write floor. Now: (1) e-unroll x2 -- each weight fragment read feeds TWO 16-pair subtiles
// (2 MFMAs per read), weight reads 68->32; (2) biases live in 32 registers (loaded once
// from the prepacked image), killing the 16 bias reads. launch_bounds(256,3) (cap 170,
// no spill, reg peak ~140). Staging/prep/gather/store identical to R10.

typedef __attribute__((ext_vector_type(8))) __bf16 bf16x8;
typedef __attribute__((ext_vector_type(4))) __bf16 bf16x4;
typedef __attribute__((ext_vector_type(4))) float  f32x4;

#define E_TOT 131072
#define N_TOK 4096
#define ROWS_PER_BLOCK 256
#define NSUB 4   // per wave: 4 subtiles x 16 pairs (4 waves -> 256 rows/block)
#define Z_ELEMS (4 * N_TOK * 64)
#define WIMG_OFF (Z_ELEMS * 2)          // byte offset of weight image in d_ws (after bf16 z)
#define WIMG_B1 32768                   // f32[64]
#define WIMG_B2 33024                   // f32[64]

__device__ __forceinline__ bf16x8 pk8(float4 a, float4 b) {
    bf16x8 r;
    r[0] = (__bf16)a.x; r[1] = (__bf16)a.y; r[2] = (__bf16)a.z; r[3] = (__bf16)a.w;
    r[4] = (__bf16)b.x; r[5] = (__bf16)b.y; r[6] = (__bf16)b.z; r[7] = (__bf16)b.w;
    return r;
}
__device__ __forceinline__ float4 f4add(float4 a, float4 b){ return make_float4(a.x+b.x, a.y+b.y, a.z+b.z, a.w+b.w); }
__device__ __forceinline__ float4 f4sub(float4 a, float4 b){ return make_float4(a.x-b.x, a.y-b.y, a.z-b.z, a.w-b.w); }

// ---- prep: blocks 0..511 cast z f32->bf16; block 512 packs the swizzled weight image ----
__global__ __launch_bounds__(256) void prep_kernel(
    const float* __restrict__ z, const float* __restrict__ W1, const float* __restrict__ b1,
    const float* __restrict__ W2, const float* __restrict__ b2,
    __bf16* __restrict__ zw, char* __restrict__ wimg)
{
    const int tid = threadIdx.x;
    const int blk = blockIdx.x;
    if (blk < 512) {
        const int t = blk * 256 + tid;
        const float4 a = ((const float4*)z)[2 * t];
        const float4 b = ((const float4*)z)[2 * t + 1];
        ((bf16x8*)zw)[t] = pk8(a, b);
        return;
    }
    const int part = tid >> 6;            // 0:zi 1:zj 2:pr 3:W2
    const int scol = tid & 63;
    const int cswz = (scol & 7) << 4;
    if (part < 3) {
        const float* wr = W1 + (size_t)scol * 256;
        char* dst = wimg + scol * 384;
#pragma unroll
        for (int c8 = 0; c8 < 8; ++c8) {
            float4 p0, p1;
            if (part == 0) {
                float4 a0 = *(const float4*)(wr + c8*8);
                float4 a1 = *(const float4*)(wr + c8*8 + 4);
                float4 c0 = *(const float4*)(wr + 128 + c8*8);
                float4 c1 = *(const float4*)(wr + 128 + c8*8 + 4);
                p0 = f4add(a0, c0); p1 = f4add(a1, c1);
            } else if (part == 1) {
                float4 a0 = *(const float4*)(wr + 64 + c8*8);
                float4 a1 = *(const float4*)(wr + 64 + c8*8 + 4);
                float4 c0 = *(const float4*)(wr + 128 + c8*8);
                float4 c1 = *(const float4*)(wr + 128 + c8*8 + 4);
                p0 = f4sub(a0, c0); p1 = f4sub(a1, c1);
            } else {
                p0 = *(const float4*)(wr + 192 + c8*8);
                p1 = *(const float4*)(wr + 192 + c8*8 + 4);
            }
            *(bf16x8*)(dst + ((part * 128 + c8 * 16) ^ cswz)) = pk8(p0, p1);
        }
    } else {
        const float* wr = W2 + (size_t)scol * 64;
        char* dst = wimg + 24576 + scol * 128;
#pragma unroll
        for (int c8 = 0; c8 < 8; ++c8) {
            float4 p0 = *(const float4*)(wr + c8*8);
            float4 p1 = *(const float4*)(wr + c8*8 + 4);
            *(bf16x8*)(dst + ((c8 * 16) ^ cswz)) = pk8(p0, p1);
        }
    }
    if (tid < 64)            *(float*)(wimg + WIMG_B1 + 4 * tid) = b1[tid];
    else if (tid < 128)      *(float*)(wimg + WIMG_B2 + 4 * (tid - 64)) = b2[tid - 64];
}

__device__ __forceinline__ f32x4 mfma16(bf16x8 a, bf16x8 b, f32x4 c) {
    return __builtin_amdgcn_mfma_f32_16x16x32_bf16(a, b, c, 0, 0, 0);
}

__device__ __forceinline__ bf16x8 bmul(bf16x8 a, bf16x8 b) {
    bf16x8 r;
#pragma unroll
    for (int t = 0; t < 8; ++t)
        r[t] = (__bf16)((float)a[t] * (float)b[t]);
    return r;
}

__global__ __launch_bounds__(256, 3) void PairRelationEncoder_62775241998442_kernel(
    const __bf16* __restrict__ zw, const char* __restrict__ wimg,
    const int* __restrict__ pairs, float* __restrict__ out)
{
    const int tid  = threadIdx.x;
    const int wave = tid >> 6;
    const int lane = tid & 63;
    const int x = lane & 15;   // e-index within subtile (B-col / C-col)
    const int g = lane >> 4;   // k-group

    // bijective XCD-chunked swizzle (2048 blocks, 8 XCDs)
    const int bid = (int)(blockIdx.x & 7) * 256 + ((int)blockIdx.x >> 3);
    const int m0 = bid * ROWS_PER_BLOCK;
    const int b  = m0 >> 17;
    const int e0 = m0 & (E_TOT - 1);
    const __bf16* zb = zw + ((size_t)b * N_TOK * 64);

    // hoisted pairs
    int2 ijv[NSUB];
#pragma unroll
    for (int st = 0; st < NSUB; ++st)
        ijv[st] = *(const int2*)(pairs + 2 * (size_t)(e0 + (st * 4 + wave) * 16 + x));

    // biases in registers (broadcast loads from the prepacked image, once)
    f32x4 b1v[4], b2v[4];
#pragma unroll
    for (int ct = 0; ct < 4; ++ct) {
        b1v[ct] = *(const f32x4*)(wimg + WIMG_B1 + (ct * 16 + g * 4) * 4);
        b2v[ct] = *(const f32x4*)(wimg + WIMG_B2 + (ct * 16 + g * 4) * 4);
    }

    // LDS: weight image (32768) + per-wave h1^T x2 subtiles (16384). 49152 B -> 3 blocks/CU.
    __shared__ char   wall[32768];
    __shared__ __bf16 h1s[4][2048];
    __bf16* h1A = h1s[wave];
    __bf16* h1B = h1s[wave] + 1024;
    const char* w1b = wall;
    const char* w2b = wall + 24576;

    // ---- staging = pure copy of the prepacked image ----
#pragma unroll
    for (int r = 0; r < 8; ++r) {
        const int off = (r * 256 + tid) * 16;
        float4 v = *(const float4*)(wimg + off);
        *(float4*)(wall + off) = v;
    }

    __syncthreads();

    const int sw = (x & 7) << 4;

#pragma unroll
    for (int sup = 0; sup < 2; ++sup) {
        const int stA = 2 * sup, stB = 2 * sup + 1;
        const __bf16* zriA = zb + (size_t)ijv[stA].x * 64;
        const __bf16* zrjA = zb + (size_t)ijv[stA].y * 64;
        const __bf16* zriB = zb + (size_t)ijv[stB].x * 64;
        const __bf16* zrjB = zb + (size_t)ijv[stB].y * 64;

        // ---- layer 1 (transposed), two subtiles per weight read ----
        f32x4 accA[4], accB[4];
#pragma unroll
        for (int ct = 0; ct < 4; ++ct) { accA[ct] = b1v[ct]; accB[ct] = b1v[ct]; }

#pragma unroll
        for (int h = 0; h < 2; ++h) {
            bf16x8 azfA = *(const bf16x8*)(zriA + h * 32 + g * 8);
            bf16x8 bzfA = *(const bf16x8*)(zrjA + h * 32 + g * 8);
            bf16x8 pzfA = bmul(azfA, bzfA);
            bf16x8 azfB = *(const bf16x8*)(zriB + h * 32 + g * 8);
            bf16x8 bzfB = *(const bf16x8*)(zrjB + h * 32 + g * 8);
            bf16x8 pzfB = bmul(azfB, bzfB);
            const int kb = h * 64 + g * 16;
#pragma unroll
            for (int ct = 0; ct < 4; ++ct) {
                const char* wb = w1b + (ct * 16 + x) * 384;
                bf16x8 wzi = *(const bf16x8*)(wb + ((kb      ) ^ sw));
                bf16x8 wzj = *(const bf16x8*)(wb + ((kb + 128) ^ sw));
                bf16x8 wpr = *(const bf16x8*)(wb + ((kb + 256) ^ sw));
                accA[ct] = mfma16(wzi, azfA, accA[ct]);
                accB[ct] = mfma16(wzi, azfB, accB[ct]);
                accA[ct] = mfma16(wzj, bzfA, accA[ct]);
                accB[ct] = mfma16(wzj, bzfB, accB[ct]);
                accA[ct] = mfma16(wpr, pzfA, accA[ct]);
                accB[ct] = mfma16(wpr, pzfB, accB[ct]);
            }
        }

        // ---- epilogue: relu, pack, ds_write_b64 x2 per ct (wave-private) ----
#pragma unroll
        for (int ct = 0; ct < 4; ++ct) {
            bf16x4 pA, pB;
#pragma unroll
            for (int q = 0; q < 4; ++q) {
                pA[q] = (__bf16)fmaxf(accA[ct][q], 0.f);
                pB[q] = (__bf16)fmaxf(accB[ct][q], 0.f);
            }
            const int wo = (x * 128 + ct * 32 + g * 8) ^ sw;
            *(bf16x4*)((char*)h1A + wo) = pA;
            *(bf16x4*)((char*)h1B + wo) = pB;
        }

        // ---- layer 2 (transposed), two subtiles per W2 read ----
        f32x4 oA[4], oB[4];
#pragma unroll
        for (int ct = 0; ct < 4; ++ct) { oA[ct] = b2v[ct]; oB[ct] = b2v[ct]; }

#pragma unroll
        for (int kk = 0; kk < 2; ++kk) {
            const int aoff = (x * 128 + kk * 64 + g * 16) ^ sw;
            const bf16x8 h1fA = *(const bf16x8*)((const char*)h1A + aoff);
            const bf16x8 h1fB = *(const bf16x8*)((const char*)h1B + aoff);
#pragma unroll
            for (int ct = 0; ct < 4; ++ct) {
                const bf16x8 w2f = *(const bf16x8*)(w2b + (ct * 16 + x) * 128
                                                    + ((kk * 64 + g * 16) ^ sw));
                oA[ct] = mfma16(w2f, h1fA, oA[ct]);
                oB[ct] = mfma16(w2f, h1fB, oB[ct]);
            }
        }

        // ---- store: 4x dwordx4 per subtile ----
        float* orowA = out + ((size_t)(m0 + (stA * 4 + wave) * 16 + x)) * 64;
        float* orowB = out + ((size_t)(m0 + (stB * 4 + wave) * 16 + x)) * 64;
#pragma unroll
        for (int ct = 0; ct < 4; ++ct) {
            *(f32x4*)(orowA + ct * 16 + g * 4) = oA[ct];
            *(f32x4*)(orowB + ct * 16 + g * 4) = oB[ct];
        }
    }
}

extern "C" void kernel_launch(void* const* d_in, const int* in_sizes, int n_in,
                              void* d_out, int out_size, void* d_ws, size_t ws_size,
                              hipStream_t stream) {
    const float* z     = (const float*)d_in[0];
    const int*   pairs = (const int*)  d_in[1];
    const float* W1    = (const float*)d_in[2];
    const float* b1    = (const float*)d_in[3];
    const float* W2    = (const float*)d_in[4];
    const float* b2    = (const float*)d_in[5];
    float* out = (float*)d_out;
    __bf16* zw  = (__bf16*)d_ws;                   // 2 MB bf16 copy of z
    char*   img = (char*)d_ws + WIMG_OFF;          // 33 KB packed+swizzled weight image

    prep_kernel<<<513, 256, 0, stream>>>(z, W1, b1, W2, b2, zw, img);

    const int total_rows = 4 * E_TOT;              // 524288
    dim3 grid(total_rows / ROWS_PER_BLOCK);        // 2048
    PairRelationEncoder_62775241998442_kernel<<<grid, 256, 0, stream>>>(
        zw, img, pairs, out);
}